// Round 3
// baseline (151.117 us; speedup 1.0000x reference)
//
#include <hip/hip_runtime.h>
#include <hip/hip_cooperative_groups.h>

namespace cg = cooperative_groups;

#define BB 8
#define DD 64
#define SS 65536          // H*W = 256*256
#define KK 17
#define NMAX 8
#define SIGMA2_INV 100.0f // 1/(0.1*0.1)

#define GRID_BLOCKS 256
#define BLOCK_THREADS 1024

// ---------------------------------------------------------------------------
// Fused kernel:
//   Phase 1 (all blocks): scan tags [B][K][S] (int32), gather x[b,:,s] into
//     e[b][t-1][k][:] (ws). Every e slot is written every call.
//   grid.sync()
//   Phase 2 (block 0 only): single pass over e computing means (LDS) + pull
//     via sum-of-squares identity, then push over ordered pairs.
// Deterministic: fixed reduction tree, no float atomics.
// ---------------------------------------------------------------------------
__global__ __launch_bounds__(BLOCK_THREADS, 4)
void fused_loss_kernel(const int* __restrict__ tags,
                       const float* __restrict__ x,
                       float* __restrict__ e,
                       const int* __restrict__ numH_raw,
                       float* __restrict__ out) {
    // ---------------- Phase 1: scan + gather ----------------
    {
        const long total4 = (long)BB * KK * SS / 4;
        long idx = (long)blockIdx.x * blockDim.x + threadIdx.x;
        long stride = (long)gridDim.x * blockDim.x;
        const int4* t4 = (const int4*)tags;
        for (long i = idx; i < total4; i += stride) {
            int4 v = t4[i];
            if ((v.x | v.y | v.z | v.w) != 0) {      // rare path
                int vv[4] = {v.x, v.y, v.z, v.w};
                #pragma unroll
                for (int j = 0; j < 4; ++j) {
                    int t = vv[j];
                    if (t > 0) {
                        long lin = i * 4 + j;        // index in [0, B*K*S)
                        int s  = (int)(lin & (SS - 1));
                        int bk = (int)(lin >> 16);   // S = 2^16
                        int b  = bk / KK;
                        int k  = bk - b * KK;
                        int n  = t - 1;
                        float*       dst = e + (((b * NMAX + n) * KK + k) * DD);
                        const float* src = x + (long)b * DD * SS + s;
                        #pragma unroll
                        for (int d = 0; d < DD; ++d)
                            dst[d] = src[(long)d * SS];
                    }
                }
            }
        }
    }

    __threadfence();            // release e writes to device scope
    cg::this_grid().sync();     // all e slots written & visible

    // ---------------- Phase 2: loss (block 0 only) ----------------
    if (blockIdx.x != 0) return;

    __shared__ float mean[BB * NMAX * DD];   // 16 KiB
    __shared__ float red[16];
    const int tid = threadIdx.x;

    // numH dtype heuristic: if stored as int64 (little-endian), raw[1] == 0.
    const int stride_n = (numH_raw[1] == 0) ? 2 : 1;

    float acc = 0.f;

    // Pass over e: per (b,n,d) sum and sum-of-squares over k.
    // pull contribution = ss - s^2/K ; mean -> LDS for push.
    for (int i = tid; i < BB * NMAX * DD; i += BLOCK_THREADS) {
        int d  = i & (DD - 1);
        int bn = i >> 6;                      // (b*NMAX + n)
        const float* ep = e + bn * (KK * DD) + d;
        float s = 0.f, ss = 0.f;
        #pragma unroll
        for (int k = 0; k < KK; ++k) {
            float v = ep[k * DD];
            s  += v;
            ss += v * v;
        }
        mean[i] = s * (1.0f / KK);
        int b = bn >> 3;
        int n = bn & (NMAX - 1);
        if (n < numH_raw[b * stride_n])
            acc += ss - s * s * (1.0f / KK);
    }
    __syncthreads();

    // push = sum over b, ordered pairs n1 != n2 (both valid)
    for (int p = tid; p < BB * NMAX * NMAX; p += BLOCK_THREADS) {
        int b  = p >> 6;
        int n1 = (p >> 3) & 7;
        int n2 = p & 7;
        int nh = numH_raw[b * stride_n];
        if (n1 != n2 && n1 < nh && n2 < nh) {
            const float* m1 = mean + (b * NMAX + n1) * DD;
            const float* m2 = mean + (b * NMAX + n2) * DD;
            float d2 = 0.f;
            #pragma unroll
            for (int d = 0; d < DD; ++d) {
                float df = m1[d] - m2[d];
                d2 += df * df;
            }
            acc += __expf(-d2 * SIGMA2_INV);
        }
    }

    // Deterministic block reduction: wave64 shuffle tree + fixed-order LDS sum
    const int lane = tid & 63, wid = tid >> 6;
    #pragma unroll
    for (int off = 32; off > 0; off >>= 1)
        acc += __shfl_down(acc, off);
    if (lane == 0) red[wid] = acc;
    __syncthreads();
    if (tid == 0) {
        float tot = 0.f;
        #pragma unroll
        for (int w = 0; w < 16; ++w) tot += red[w];
        out[0] = tot;
    }
}

extern "C" void kernel_launch(void* const* d_in, const int* in_sizes, int n_in,
                              void* d_out, int out_size, void* d_ws, size_t ws_size,
                              hipStream_t stream) {
    const int*   tags = (const int*)d_in[1];
    const float* x    = (const float*)d_in[0];
    const int*   numH = (const int*)d_in[2];
    float*       out  = (float*)d_out;
    float*       e    = (float*)d_ws;   // e[B][NMAX][K][D] = 278,528 bytes

    void* args[] = {(void*)&tags, (void*)&x, (void*)&e, (void*)&numH, (void*)&out};
    hipLaunchCooperativeKernel((const void*)fused_loss_kernel,
                               dim3(GRID_BLOCKS), dim3(BLOCK_THREADS),
                               args, 0, stream);
}

// Round 4
// 106.994 us; speedup vs baseline: 1.4124x; 1.4124x over previous
//
#include <hip/hip_runtime.h>

#define BB 8
#define DD 64
#define SS 65536          // H*W = 256*256
#define KK 17
#define NMAX 8
#define SIGMA2_INV 100.0f // 1/(0.1*0.1)

#define GRID_BLOCKS 256
#define BLOCK_THREADS 1024
#define E_ELEMS (BB * NMAX * KK * DD)     // 69632 floats = 278528 bytes

// ---------------------------------------------------------------------------
// Single fused kernel (ordinary launch, no cooperative groups):
//  Phase 1 (all blocks): grid-stride scan of tags [B][K][S] int32 as int4.
//    On a hit, the whole wave gathers x[b, lane, s] -> e[b][t-1][k][lane]
//    (D == wave size == 64, so one load + one coalesced store per hit).
//  Handshake: __threadfence + atomicAdd on a ws counter (zeroed each call by
//    a 4-byte hipMemsetAsync). The block observing old == GRID_BLOCKS-1 knows
//    every other block has released its e writes.
//  Phase 2 (last block only): one pass over e -> means (LDS) + pull via
//    ss - s^2/K identity; then push over ordered instance pairs.
//  Deterministic: fixed reduction tree, integer atomics only.
// ---------------------------------------------------------------------------
__global__ __launch_bounds__(BLOCK_THREADS)
void fused_kernel(const int* __restrict__ tags,
                  const float* __restrict__ x,
                  float* __restrict__ e,
                  unsigned int* __restrict__ counter,
                  const int* __restrict__ numH_raw,
                  float* __restrict__ out) {
    const int lane = threadIdx.x & 63;

    // ---------------- Phase 1: scan + wave-cooperative gather ----------------
    {
        const int total4 = BB * KK * SS / 4;          // 2,228,224 int4s
        const int stride = GRID_BLOCKS * BLOCK_THREADS;
        const int4* t4 = (const int4*)tags;
        for (int i = blockIdx.x * BLOCK_THREADS + threadIdx.x; i < total4; i += stride) {
            int4 v = t4[i];
            bool hit = (v.x | v.y | v.z | v.w) != 0;  // tags >= 0
            unsigned long long m = __ballot(hit);
            while (m) {                                // wave-uniform loop
                int sl = __ffsll((long long)m) - 1;
                m &= m - 1;
                int c0 = __shfl(v.x, sl), c1 = __shfl(v.y, sl),
                    c2 = __shfl(v.z, sl), c3 = __shfl(v.w, sl);
                int ibase = __shfl(i, sl) * 4;
                int comp[4] = {c0, c1, c2, c3};
                #pragma unroll
                for (int j = 0; j < 4; ++j) {
                    int t = comp[j];
                    if (t > 0) {                       // uniform branch
                        int lin = ibase + j;           // element in [0, B*K*S)
                        int s  = lin & (SS - 1);
                        int bk = lin >> 16;            // S = 2^16
                        int b  = bk / KK;
                        int k  = bk - b * KK;
                        int n  = t - 1;
                        // lane d loads x[b][d][s]; coalesced 256B store to e
                        float val = x[(size_t)(b * DD + lane) * SS + s];
                        e[((b * NMAX + n) * KK + k) * DD + lane] = val;
                    }
                }
            }
        }
    }

    // ---------------- Handshake: last block to finish runs the loss ----------
    __shared__ int is_last;
    __threadfence();                                  // release e writes
    __syncthreads();
    if (threadIdx.x == 0) {
        unsigned int old = atomicAdd(counter, 1u);    // device-scope
        is_last = (old == GRID_BLOCKS - 1);
    }
    __syncthreads();
    if (!is_last) return;
    __threadfence();                                  // acquire e writes

    // ---------------- Phase 2: loss (last block only) ------------------------
    __shared__ float mean[BB * NMAX * DD];            // 16 KiB
    __shared__ float red[16];
    const int tid = threadIdx.x;

    // numH dtype heuristic: if stored as int64 (little-endian), raw[1] == 0.
    const int stride_n = (numH_raw[1] == 0) ? 2 : 1;

    float acc = 0.f;

    // One pass over e: per (b,n,d) sum + sum-of-squares over k.
    // pull contribution = ss - s^2/K ; mean -> LDS for push.
    for (int i = tid; i < BB * NMAX * DD; i += BLOCK_THREADS) {
        int d  = i & (DD - 1);
        int bn = i >> 6;                              // (b*NMAX + n)
        const float* ep = e + bn * (KK * DD) + d;
        float s = 0.f, ss = 0.f;
        #pragma unroll
        for (int k = 0; k < KK; ++k) {
            float v = ep[k * DD];
            s  += v;
            ss += v * v;
        }
        mean[i] = s * (1.0f / KK);
        int b = bn >> 3;
        int n = bn & (NMAX - 1);
        if (n < numH_raw[b * stride_n])
            acc += ss - s * s * (1.0f / KK);
    }
    __syncthreads();

    // push = sum over b, ordered pairs n1 != n2 (both valid)
    for (int p = tid; p < BB * NMAX * NMAX; p += BLOCK_THREADS) {
        int b  = p >> 6;
        int n1 = (p >> 3) & 7;
        int n2 = p & 7;
        int nh = numH_raw[b * stride_n];
        if (n1 != n2 && n1 < nh && n2 < nh) {
            const float* m1 = mean + (b * NMAX + n1) * DD;
            const float* m2 = mean + (b * NMAX + n2) * DD;
            float d2 = 0.f;
            #pragma unroll
            for (int d = 0; d < DD; ++d) {
                float df = m1[d] - m2[d];
                d2 += df * df;
            }
            acc += __expf(-d2 * SIGMA2_INV);
        }
    }

    // Deterministic block reduction: wave64 shuffle tree + fixed-order LDS sum
    const int wlane = tid & 63, wid = tid >> 6;
    #pragma unroll
    for (int off = 32; off > 0; off >>= 1)
        acc += __shfl_down(acc, off);
    if (wlane == 0) red[wid] = acc;
    __syncthreads();
    if (tid == 0) {
        float tot = 0.f;
        #pragma unroll
        for (int w = 0; w < 16; ++w) tot += red[w];
        out[0] = tot;
    }
}

extern "C" void kernel_launch(void* const* d_in, const int* in_sizes, int n_in,
                              void* d_out, int out_size, void* d_ws, size_t ws_size,
                              hipStream_t stream) {
    const float* x    = (const float*)d_in[0];
    const int*   tags = (const int*)d_in[1];
    const int*   numH = (const int*)d_in[2];
    float*       out  = (float*)d_out;
    float*       e    = (float*)d_ws;                         // 278528 B
    unsigned int* counter = (unsigned int*)((char*)d_ws + E_ELEMS * sizeof(float));

    hipMemsetAsync(counter, 0, sizeof(unsigned int), stream); // re-arm handshake

    fused_kernel<<<GRID_BLOCKS, BLOCK_THREADS, 0, stream>>>(tags, x, e, counter,
                                                            numH, out);
}

// Round 5
// 28.300 us; speedup vs baseline: 5.3399x; 3.7808x over previous
//
#include <hip/hip_runtime.h>

#define BB 8
#define DD 64
#define SS 65536          // H*W = 256*256
#define KK 17
#define NMAX 8
#define SIGMA2_INV 100.0f // 1/(0.1*0.1)

#define GRID_BLOCKS 512
#define BLOCK_THREADS 1024
#define E_ELEMS (BB * NMAX * KK * DD)     // 69632 floats = 278528 bytes

// ---------------------------------------------------------------------------
// Single fused kernel, NO cache-walk fences (lesson from R3/R4: per-wave
// __threadfence / grid.sync cost ~120us in L2 writeback/invalidate ops).
// Cross-XCD visibility of e is instead achieved with relaxed AGENT-scope
// atomic stores (write-through to coherent point) and relaxed AGENT-scope
// atomic loads (bypass stale caches). Ordering: __syncthreads() drains vmcnt
// (compiler emits full s_waitcnt before s_barrier), so every block's coherent
// stores are complete before its counter increment.
//  Phase 1 (all blocks): grid-stride scan of tags [B][K][S] int32 as int4.
//    On a hit, the whole wave gathers x[b, lane, s] -> e[b][t-1][k][lane].
//  Phase 2 (last block per counter): one pass over e -> means (LDS) + pull
//    via ss - s^2/K identity; then push over ordered instance pairs.
//  Deterministic: distinct-address stores, fixed reduction tree, int atomics.
// ---------------------------------------------------------------------------
__global__ __launch_bounds__(BLOCK_THREADS)
void fused_kernel(const int* __restrict__ tags,
                  const float* __restrict__ x,
                  float* __restrict__ e,
                  unsigned int* __restrict__ counter,
                  const int* __restrict__ numH_raw,
                  float* __restrict__ out) {
    const int lane = threadIdx.x & 63;

    // ---------------- Phase 1: scan + wave-cooperative gather ----------------
    {
        const int total4 = BB * KK * SS / 4;          // 2,228,224 int4s
        const int stride = GRID_BLOCKS * BLOCK_THREADS;
        const int4* t4 = (const int4*)tags;
        for (int i = blockIdx.x * BLOCK_THREADS + threadIdx.x; i < total4; i += stride) {
            int4 v = t4[i];
            bool hit = (v.x | v.y | v.z | v.w) != 0;  // tags >= 0
            unsigned long long m = __ballot(hit);
            while (m) {                                // wave-uniform loop
                int sl = __ffsll((long long)m) - 1;
                m &= m - 1;
                int c0 = __shfl(v.x, sl), c1 = __shfl(v.y, sl),
                    c2 = __shfl(v.z, sl), c3 = __shfl(v.w, sl);
                int ibase = __shfl(i, sl) * 4;
                int comp[4] = {c0, c1, c2, c3};
                #pragma unroll
                for (int j = 0; j < 4; ++j) {
                    int t = comp[j];
                    if (t > 0) {                       // wave-uniform branch
                        int lin = ibase + j;           // element in [0, B*K*S)
                        int s  = lin & (SS - 1);
                        int bk = lin >> 16;            // S = 2^16
                        int b  = bk / KK;
                        int k  = bk - b * KK;
                        int n  = t - 1;
                        // lane d loads x[b][d][s]; coherent store to e
                        float val = x[(size_t)(b * DD + lane) * SS + s];
                        __hip_atomic_store(&e[((b * NMAX + n) * KK + k) * DD + lane],
                                           val, __ATOMIC_RELAXED,
                                           __HIP_MEMORY_SCOPE_AGENT);
                    }
                }
            }
        }
    }

    // ------------- Handshake: last block to finish runs the loss -------------
    __shared__ int is_last;
    __syncthreads();                                  // drains vmcnt: stores done
    if (threadIdx.x == 0) {
        unsigned int old = atomicAdd(counter, 1u);    // device-scope RMW
        is_last = (old == GRID_BLOCKS - 1);
    }
    __syncthreads();
    if (!is_last) return;

    // ---------------- Phase 2: loss (last block only) ------------------------
    __shared__ float mean[BB * NMAX * DD];            // 16 KiB
    __shared__ float red[16];
    const int tid = threadIdx.x;

    // numH dtype heuristic: if stored as int64 (little-endian), raw[1] == 0.
    const int stride_n = (numH_raw[1] == 0) ? 2 : 1;

    float acc = 0.f;

    // One pass over e (coherent loads): per (b,n,d) sum + sum-of-squares over k.
    // pull contribution = ss - s^2/K ; mean -> LDS for push.
    for (int i = tid; i < BB * NMAX * DD; i += BLOCK_THREADS) {
        int d  = i & (DD - 1);
        int bn = i >> 6;                              // (b*NMAX + n)
        float* ep = e + bn * (KK * DD) + d;
        float s = 0.f, ss = 0.f;
        #pragma unroll
        for (int k = 0; k < KK; ++k) {
            float v = __hip_atomic_load(&ep[k * DD], __ATOMIC_RELAXED,
                                        __HIP_MEMORY_SCOPE_AGENT);
            s  += v;
            ss += v * v;
        }
        mean[i] = s * (1.0f / KK);
        int b = bn >> 3;
        int n = bn & (NMAX - 1);
        if (n < numH_raw[b * stride_n])
            acc += ss - s * s * (1.0f / KK);
    }
    __syncthreads();

    // push = sum over b, ordered pairs n1 != n2 (both valid)
    for (int p = tid; p < BB * NMAX * NMAX; p += BLOCK_THREADS) {
        int b  = p >> 6;
        int n1 = (p >> 3) & 7;
        int n2 = p & 7;
        int nh = numH_raw[b * stride_n];
        if (n1 != n2 && n1 < nh && n2 < nh) {
            const float* m1 = mean + (b * NMAX + n1) * DD;
            const float* m2 = mean + (b * NMAX + n2) * DD;
            float d2 = 0.f;
            #pragma unroll
            for (int d = 0; d < DD; ++d) {
                float df = m1[d] - m2[d];
                d2 += df * df;
            }
            acc += __expf(-d2 * SIGMA2_INV);
        }
    }

    // Deterministic block reduction: wave64 shuffle tree + fixed-order LDS sum
    const int wlane = tid & 63, wid = tid >> 6;
    #pragma unroll
    for (int off = 32; off > 0; off >>= 1)
        acc += __shfl_down(acc, off);
    if (wlane == 0) red[wid] = acc;
    __syncthreads();
    if (tid == 0) {
        float tot = 0.f;
        #pragma unroll
        for (int w = 0; w < 16; ++w) tot += red[w];
        out[0] = tot;
    }
}

extern "C" void kernel_launch(void* const* d_in, const int* in_sizes, int n_in,
                              void* d_out, int out_size, void* d_ws, size_t ws_size,
                              hipStream_t stream) {
    const float* x    = (const float*)d_in[0];
    const int*   tags = (const int*)d_in[1];
    const int*   numH = (const int*)d_in[2];
    float*       out  = (float*)d_out;
    float*       e    = (float*)d_ws;                         // 278528 B
    unsigned int* counter = (unsigned int*)((char*)d_ws + E_ELEMS * sizeof(float));

    hipMemsetAsync(counter, 0, sizeof(unsigned int), stream); // re-arm handshake

    fused_kernel<<<GRID_BLOCKS, BLOCK_THREADS, 0, stream>>>(tags, x, e, counter,
                                                            numH, out);
}

// Round 6
// 19.829 us; speedup vs baseline: 7.6209x; 1.4272x over previous
//
#include <hip/hip_runtime.h>

#define BB 8
#define DD 64
#define SS 65536          // H*W = 256*256
#define KK 17
#define NMAX 8
#define SIGMA2_INV 100.0f // 1/(0.1*0.1)

#define SCAN_BLOCKS 2048
#define SCAN_THREADS 256

// ---------------------------------------------------------------------------
// Kernel 1: grid-stride scan of tags [B][K][S] int32 as int4.
// On a hit (tag t>0 at (b,k,s)), the WHOLE wave gathers x[b, lane, s] ->
// e[b][t-1][k][lane]: one strided load + one coalesced 256B store per hit
// (D == 64 == wave width). Hit path fires B*K*NMAX = 1088 times total.
// Plain cached stores; the kernel-boundary release/acquire makes e coherent
// for kernel 2 (lesson R3-R5: never fence in-kernel for us-scale work).
// ---------------------------------------------------------------------------
__global__ __launch_bounds__(SCAN_THREADS)
void scan_gather_kernel(const int* __restrict__ tags,
                        const float* __restrict__ x,
                        float* __restrict__ e) {
    const int lane = threadIdx.x & 63;
    const int total4 = BB * KK * SS / 4;              // 2,228,224 int4s
    const int stride = SCAN_BLOCKS * SCAN_THREADS;
    const int4* t4 = (const int4*)tags;
    for (int i = blockIdx.x * SCAN_THREADS + threadIdx.x; i < total4; i += stride) {
        int4 v = t4[i];
        bool hit = (v.x | v.y | v.z | v.w) != 0;      // tags >= 0
        unsigned long long m = __ballot(hit);
        while (m) {                                    // wave-uniform loop
            int sl = __ffsll((long long)m) - 1;
            m &= m - 1;
            int c0 = __shfl(v.x, sl), c1 = __shfl(v.y, sl),
                c2 = __shfl(v.z, sl), c3 = __shfl(v.w, sl);
            int ibase = __shfl(i, sl) * 4;
            int comp[4] = {c0, c1, c2, c3};
            #pragma unroll
            for (int j = 0; j < 4; ++j) {
                int t = comp[j];
                if (t > 0) {                           // wave-uniform branch
                    int lin = ibase + j;               // element in [0, B*K*S)
                    int s  = lin & (SS - 1);
                    int bk = lin >> 16;                // S = 2^16
                    int b  = bk / KK;
                    int k  = bk - b * KK;
                    int n  = t - 1;
                    float val = x[(size_t)(b * DD + lane) * SS + s];
                    e[((b * NMAX + n) * KK + k) * DD + lane] = val;
                }
            }
        }
    }
}

// ---------------------------------------------------------------------------
// Kernel 2: one block, 1024 threads, float4 single pass over e.
// Phase A: thread t owns (bn, d4) = (t>>4, t&15): 17 independent float4
//   loads (stride 256B), per-component sum + sumsq ->
//   pull contribution  ss - s^2/K ; mean (float4) -> LDS.
// Phase B: push over 512 ordered pairs, float4 LDS reads.
// Deterministic: fixed reduction tree, no float atomics.
// ---------------------------------------------------------------------------
__global__ __launch_bounds__(1024)
void loss_kernel(const float4* __restrict__ e4,
                 const int* __restrict__ numH_raw,
                 float* __restrict__ out) {
    __shared__ float mean[BB * NMAX * DD];            // 16 KiB
    __shared__ float red[16];
    const int tid = threadIdx.x;

    // numH dtype heuristic: if stored as int64 (little-endian), raw[1] == 0.
    const int stride_n = (numH_raw[1] == 0) ? 2 : 1;

    float acc = 0.f;

    // ---- Phase A: exactly 1024 (bn,d4) groups for 1024 threads ----
    {
        const int bn = tid >> 4;                      // (b*NMAX + n), 0..63
        const int q  = tid & 15;                      // float4 index in D
        const float4* ep = e4 + bn * (KK * 16) + q;
        float s0 = 0.f, s1 = 0.f, s2 = 0.f, s3 = 0.f;
        float q0 = 0.f, q1 = 0.f, q2 = 0.f, q3 = 0.f;
        #pragma unroll
        for (int k = 0; k < KK; ++k) {
            float4 v = ep[k * 16];
            s0 += v.x; q0 += v.x * v.x;
            s1 += v.y; q1 += v.y * v.y;
            s2 += v.z; q2 += v.z * v.z;
            s3 += v.w; q3 += v.w * v.w;
        }
        float4 mv;
        mv.x = s0 * (1.0f / KK); mv.y = s1 * (1.0f / KK);
        mv.z = s2 * (1.0f / KK); mv.w = s3 * (1.0f / KK);
        ((float4*)mean)[bn * 16 + q] = mv;
        const int b = bn >> 3, n = bn & (NMAX - 1);
        if (n < numH_raw[b * stride_n])
            acc += (q0 - s0 * s0 * (1.0f / KK)) + (q1 - s1 * s1 * (1.0f / KK))
                 + (q2 - s2 * s2 * (1.0f / KK)) + (q3 - s3 * s3 * (1.0f / KK));
    }
    __syncthreads();

    // ---- Phase B: push over ordered pairs (512 of them) ----
    for (int p = tid; p < BB * NMAX * NMAX; p += 1024) {
        int b  = p >> 6;
        int n1 = (p >> 3) & 7;
        int n2 = p & 7;
        int nh = numH_raw[b * stride_n];
        if (n1 != n2 && n1 < nh && n2 < nh) {
            const float4* m1 = (const float4*)(mean + (b * NMAX + n1) * DD);
            const float4* m2 = (const float4*)(mean + (b * NMAX + n2) * DD);
            float d2 = 0.f;
            #pragma unroll
            for (int d = 0; d < DD / 4; ++d) {
                float4 a = m1[d], c = m2[d];
                float dx = a.x - c.x, dy = a.y - c.y,
                      dz = a.z - c.z, dw = a.w - c.w;
                d2 += dx * dx + dy * dy + dz * dz + dw * dw;
            }
            acc += __expf(-d2 * SIGMA2_INV);
        }
    }

    // Deterministic block reduction: wave64 shuffle tree + fixed-order LDS sum
    const int wlane = tid & 63, wid = tid >> 6;
    #pragma unroll
    for (int off = 32; off > 0; off >>= 1)
        acc += __shfl_down(acc, off);
    if (wlane == 0) red[wid] = acc;
    __syncthreads();
    if (tid == 0) {
        float tot = 0.f;
        #pragma unroll
        for (int w = 0; w < 16; ++w) tot += red[w];
        out[0] = tot;
    }
}

extern "C" void kernel_launch(void* const* d_in, const int* in_sizes, int n_in,
                              void* d_out, int out_size, void* d_ws, size_t ws_size,
                              hipStream_t stream) {
    const float* x    = (const float*)d_in[0];
    const int*   tags = (const int*)d_in[1];
    const int*   numH = (const int*)d_in[2];
    float*       out  = (float*)d_out;
    float*       e    = (float*)d_ws;   // e[B][NMAX][K][D] = 278,528 bytes

    scan_gather_kernel<<<SCAN_BLOCKS, SCAN_THREADS, 0, stream>>>(tags, x, e);
    loss_kernel<<<1, 1024, 0, stream>>>((const float4*)e, numH, out);
}

// Round 8
// 18.370 us; speedup vs baseline: 8.2263x; 1.0794x over previous
//
#include <hip/hip_runtime.h>

#define BB 8
#define DD 64
#define SS 65536          // H*W = 256*256
#define KK 17
#define NMAX 8
#define SIGMA2_INV 100.0f // 1/(0.1*0.1)

#define SCAN_BLOCKS 2048
#define SCAN_THREADS 256

typedef int int4v __attribute__((ext_vector_type(4)));   // clang vector (NT-load legal)

// ---------------------------------------------------------------------------
// Wave-cooperative hit handler: for each lane holding a hit int4 (some tag
// t>0), broadcast it; all 64 lanes gather x[b, lane, s] -> e[b][t-1][k][lane]
// (one strided NT load + one coalesced 256B store per hit). Fires
// B*K*NMAX = 1088 times total across the grid.
// ---------------------------------------------------------------------------
__device__ __forceinline__ void process_hits(int4v v, int i, int lane,
                                             const float* __restrict__ x,
                                             float* __restrict__ e) {
    bool hit = (v.x | v.y | v.z | v.w) != 0;          // tags >= 0
    unsigned long long m = __ballot(hit);
    while (m) {                                        // wave-uniform loop
        int sl = __ffsll((long long)m) - 1;
        m &= m - 1;
        int c0 = __shfl(v.x, sl), c1 = __shfl(v.y, sl),
            c2 = __shfl(v.z, sl), c3 = __shfl(v.w, sl);
        int ibase = __shfl(i, sl) * 4;
        int comp[4] = {c0, c1, c2, c3};
        #pragma unroll
        for (int j = 0; j < 4; ++j) {
            int t = comp[j];
            if (t > 0) {                               // wave-uniform branch
                int lin = ibase + j;                   // element in [0, B*K*S)
                int s  = lin & (SS - 1);
                int bk = lin >> 16;                    // S = 2^16
                int b  = bk / KK;
                int k  = bk - b * KK;
                int n  = t - 1;
                float val = __builtin_nontemporal_load(
                    x + (size_t)(b * DD + lane) * SS + s);
                e[((b * NMAX + n) * KK + k) * DD + lane] = val;
            }
        }
    }
}

// ---------------------------------------------------------------------------
// Kernel 1: grid-stride scan of tags [B][K][S] int32 as int4, 2x unrolled,
// nontemporal loads (tags are use-once streaming data: don't thrash L2).
// Plain cached e stores; kernel-boundary release/acquire gives coherence for
// kernel 2 (lesson R3-R5: never fence in-kernel for us-scale work).
// ---------------------------------------------------------------------------
__global__ __launch_bounds__(SCAN_THREADS)
void scan_gather_kernel(const int* __restrict__ tags,
                        const float* __restrict__ x,
                        float* __restrict__ e) {
    const int lane = threadIdx.x & 63;
    const int total4 = BB * KK * SS / 4;               // 2,228,224 int4s
    const int stride = SCAN_BLOCKS * SCAN_THREADS;     // 524,288
    const int4v* t4 = (const int4v*)tags;

    int i = blockIdx.x * SCAN_THREADS + threadIdx.x;
    for (; i + stride < total4; i += 2 * stride) {     // wave-uniform bounds
        int4v v0 = __builtin_nontemporal_load(t4 + i);
        int4v v1 = __builtin_nontemporal_load(t4 + i + stride);
        process_hits(v0, i, lane, x, e);
        process_hits(v1, i + stride, lane, x, e);
    }
    if (i < total4) {
        int4v v = __builtin_nontemporal_load(t4 + i);
        process_hits(v, i, lane, x, e);
    }
}

// ---------------------------------------------------------------------------
// Kernel 2: one block, 1024 threads, float4 single pass over e.
// Phase A: thread t owns (bn, d4) = (t>>4, t&15): 17 independent float4
//   loads (stride 256B), per-component sum + sumsq ->
//   pull contribution  ss - s^2/K ; mean (float4) -> LDS.
// Phase B: push over 512 ordered pairs, float4 LDS reads.
// Deterministic: fixed reduction tree, no float atomics.
// ---------------------------------------------------------------------------
__global__ __launch_bounds__(1024)
void loss_kernel(const float4* __restrict__ e4,
                 const int* __restrict__ numH_raw,
                 float* __restrict__ out) {
    __shared__ float mean[BB * NMAX * DD];             // 16 KiB
    __shared__ float red[16];
    const int tid = threadIdx.x;

    // numH dtype heuristic: if stored as int64 (little-endian), raw[1] == 0.
    const int stride_n = (numH_raw[1] == 0) ? 2 : 1;

    float acc = 0.f;

    // ---- Phase A: exactly 1024 (bn,d4) groups for 1024 threads ----
    {
        const int bn = tid >> 4;                       // (b*NMAX + n), 0..63
        const int q  = tid & 15;                       // float4 index in D
        const float4* ep = e4 + bn * (KK * 16) + q;
        float s0 = 0.f, s1 = 0.f, s2 = 0.f, s3 = 0.f;
        float q0 = 0.f, q1 = 0.f, q2 = 0.f, q3 = 0.f;
        #pragma unroll
        for (int k = 0; k < KK; ++k) {
            float4 v = ep[k * 16];
            s0 += v.x; q0 += v.x * v.x;
            s1 += v.y; q1 += v.y * v.y;
            s2 += v.z; q2 += v.z * v.z;
            s3 += v.w; q3 += v.w * v.w;
        }
        float4 mv;
        mv.x = s0 * (1.0f / KK); mv.y = s1 * (1.0f / KK);
        mv.z = s2 * (1.0f / KK); mv.w = s3 * (1.0f / KK);
        ((float4*)mean)[bn * 16 + q] = mv;
        const int b = bn >> 3, n = bn & (NMAX - 1);
        if (n < numH_raw[b * stride_n])
            acc += (q0 - s0 * s0 * (1.0f / KK)) + (q1 - s1 * s1 * (1.0f / KK))
                 + (q2 - s2 * s2 * (1.0f / KK)) + (q3 - s3 * s3 * (1.0f / KK));
    }
    __syncthreads();

    // ---- Phase B: push over ordered pairs (512 of them) ----
    for (int p = tid; p < BB * NMAX * NMAX; p += 1024) {
        int b  = p >> 6;
        int n1 = (p >> 3) & 7;
        int n2 = p & 7;
        int nh = numH_raw[b * stride_n];
        if (n1 != n2 && n1 < nh && n2 < nh) {
            const float4* m1 = (const float4*)(mean + (b * NMAX + n1) * DD);
            const float4* m2 = (const float4*)(mean + (b * NMAX + n2) * DD);
            float d2 = 0.f;
            #pragma unroll
            for (int d = 0; d < DD / 4; ++d) {
                float4 a = m1[d], c = m2[d];
                float dx = a.x - c.x, dy = a.y - c.y,
                      dz = a.z - c.z, dw = a.w - c.w;
                d2 += dx * dx + dy * dy + dz * dz + dw * dw;
            }
            acc += __expf(-d2 * SIGMA2_INV);
        }
    }

    // Deterministic block reduction: wave64 shuffle tree + fixed-order LDS sum
    const int wlane = tid & 63, wid = tid >> 6;
    #pragma unroll
    for (int off = 32; off > 0; off >>= 1)
        acc += __shfl_down(acc, off);
    if (wlane == 0) red[wid] = acc;
    __syncthreads();
    if (tid == 0) {
        float tot = 0.f;
        #pragma unroll
        for (int w = 0; w < 16; ++w) tot += red[w];
        out[0] = tot;
    }
}

extern "C" void kernel_launch(void* const* d_in, const int* in_sizes, int n_in,
                              void* d_out, int out_size, void* d_ws, size_t ws_size,
                              hipStream_t stream) {
    const float* x    = (const float*)d_in[0];
    const int*   tags = (const int*)d_in[1];
    const int*   numH = (const int*)d_in[2];
    float*       out  = (float*)d_out;
    float*       e    = (float*)d_ws;   // e[B][NMAX][K][D] = 278,528 bytes

    scan_gather_kernel<<<SCAN_BLOCKS, SCAN_THREADS, 0, stream>>>(tags, x, e);
    loss_kernel<<<1, 1024, 0, stream>>>((const float4*)e, numH, out);
}

// Round 9
// 18.269 us; speedup vs baseline: 8.2719x; 1.0055x over previous
//
#include <hip/hip_runtime.h>

#define BB 8
#define DD 64
#define SS 65536          // H*W = 256*256
#define KK 17
#define NMAX 8
#define SIGMA2_INV 100.0f // 1/(0.1*0.1)

#define SCAN_BLOCKS 2048
#define SCAN_THREADS 256

typedef int int4v __attribute__((ext_vector_type(4)));   // clang vector (NT-load legal)

// ---------------------------------------------------------------------------
// Wave-cooperative hit handler: for each lane holding a hit int4 (some tag
// t>0), broadcast it; all 64 lanes gather x[b, lane, s] -> e[b][t-1][k][lane]
// (one strided load + one coalesced 256B store per hit). Fires
// B*K*NMAX = 1088 times total across the grid.
// ---------------------------------------------------------------------------
__device__ __forceinline__ void process_hits(int4v v, int i, int lane,
                                             const float* __restrict__ x,
                                             float* __restrict__ e) {
    bool hit = (v.x | v.y | v.z | v.w) != 0;          // tags >= 0
    unsigned long long m = __ballot(hit);
    while (m) {                                        // wave-uniform loop
        int sl = __ffsll((long long)m) - 1;
        m &= m - 1;
        int c0 = __shfl(v.x, sl), c1 = __shfl(v.y, sl),
            c2 = __shfl(v.z, sl), c3 = __shfl(v.w, sl);
        int ibase = __shfl(i, sl) * 4;
        int comp[4] = {c0, c1, c2, c3};
        #pragma unroll
        for (int j = 0; j < 4; ++j) {
            int t = comp[j];
            if (t > 0) {                               // wave-uniform branch
                int lin = ibase + j;                   // element in [0, B*K*S)
                int s  = lin & (SS - 1);
                int bk = lin >> 16;                    // S = 2^16
                int b  = bk / KK;
                int k  = bk - b * KK;
                int n  = t - 1;
                float val = __builtin_nontemporal_load(
                    x + (size_t)(b * DD + lane) * SS + s);
                e[((b * NMAX + n) * KK + k) * DD + lane] = val;
            }
        }
    }
}

// ---------------------------------------------------------------------------
// Kernel 1: grid-stride scan of tags [B][K][S] int32 as int4, 4x unrolled
// (one fully-unrolled pass covers 4/4.25 of each thread's work; tail covers
// the rest), nontemporal loads (tags are use-once streaming data).
// Plain cached e stores; kernel-boundary release/acquire gives coherence for
// kernel 2 (lesson R3-R5: never fence in-kernel for us-scale work).
// ---------------------------------------------------------------------------
__global__ __launch_bounds__(SCAN_THREADS)
void scan_gather_kernel(const int* __restrict__ tags,
                        const float* __restrict__ x,
                        float* __restrict__ e) {
    const int lane = threadIdx.x & 63;
    const int total4 = BB * KK * SS / 4;               // 2,228,224 int4s
    const int stride = SCAN_BLOCKS * SCAN_THREADS;     // 524,288
    const int4v* t4 = (const int4v*)tags;

    int i = blockIdx.x * SCAN_THREADS + threadIdx.x;
    for (; i + 3 * stride < total4; i += 4 * stride) { // wave-uniform bounds
        int4v v0 = __builtin_nontemporal_load(t4 + i);
        int4v v1 = __builtin_nontemporal_load(t4 + i + stride);
        int4v v2 = __builtin_nontemporal_load(t4 + i + 2 * stride);
        int4v v3 = __builtin_nontemporal_load(t4 + i + 3 * stride);
        process_hits(v0, i, lane, x, e);
        process_hits(v1, i + stride, lane, x, e);
        process_hits(v2, i + 2 * stride, lane, x, e);
        process_hits(v3, i + 3 * stride, lane, x, e);
    }
    for (; i < total4; i += stride) {
        int4v v = __builtin_nontemporal_load(t4 + i);
        process_hits(v, i, lane, x, e);
    }
}

// ---------------------------------------------------------------------------
// Kernel 2: one block, 1024 threads, float4 single pass over e.
// Phase A: thread t owns (bn, d4) = (t>>4, t&15): 17 independent float4
//   loads (stride 256B), per-component sum + sumsq ->
//   pull contribution  ss - s^2/K ; mean (float4) -> LDS.
// Phase B: push over 512 ordered pairs, float4 LDS reads.
// Deterministic: fixed reduction tree, no float atomics.
// ---------------------------------------------------------------------------
__global__ __launch_bounds__(1024)
void loss_kernel(const float4* __restrict__ e4,
                 const int* __restrict__ numH_raw,
                 float* __restrict__ out) {
    __shared__ float mean[BB * NMAX * DD];             // 16 KiB
    __shared__ float red[16];
    const int tid = threadIdx.x;

    // numH dtype heuristic: if stored as int64 (little-endian), raw[1] == 0.
    const int stride_n = (numH_raw[1] == 0) ? 2 : 1;

    float acc = 0.f;

    // ---- Phase A: exactly 1024 (bn,d4) groups for 1024 threads ----
    {
        const int bn = tid >> 4;                       // (b*NMAX + n), 0..63
        const int q  = tid & 15;                       // float4 index in D
        const float4* ep = e4 + bn * (KK * 16) + q;
        float s0 = 0.f, s1 = 0.f, s2 = 0.f, s3 = 0.f;
        float q0 = 0.f, q1 = 0.f, q2 = 0.f, q3 = 0.f;
        #pragma unroll
        for (int k = 0; k < KK; ++k) {
            float4 v = ep[k * 16];
            s0 += v.x; q0 += v.x * v.x;
            s1 += v.y; q1 += v.y * v.y;
            s2 += v.z; q2 += v.z * v.z;
            s3 += v.w; q3 += v.w * v.w;
        }
        float4 mv;
        mv.x = s0 * (1.0f / KK); mv.y = s1 * (1.0f / KK);
        mv.z = s2 * (1.0f / KK); mv.w = s3 * (1.0f / KK);
        ((float4*)mean)[bn * 16 + q] = mv;
        const int b = bn >> 3, n = bn & (NMAX - 1);
        if (n < numH_raw[b * stride_n])
            acc += (q0 - s0 * s0 * (1.0f / KK)) + (q1 - s1 * s1 * (1.0f / KK))
                 + (q2 - s2 * s2 * (1.0f / KK)) + (q3 - s3 * s3 * (1.0f / KK));
    }
    __syncthreads();

    // ---- Phase B: push over ordered pairs (512 of them) ----
    for (int p = tid; p < BB * NMAX * NMAX; p += 1024) {
        int b  = p >> 6;
        int n1 = (p >> 3) & 7;
        int n2 = p & 7;
        int nh = numH_raw[b * stride_n];
        if (n1 != n2 && n1 < nh && n2 < nh) {
            const float4* m1 = (const float4*)(mean + (b * NMAX + n1) * DD);
            const float4* m2 = (const float4*)(mean + (b * NMAX + n2) * DD);
            float d2 = 0.f;
            #pragma unroll
            for (int d = 0; d < DD / 4; ++d) {
                float4 a = m1[d], c = m2[d];
                float dx = a.x - c.x, dy = a.y - c.y,
                      dz = a.z - c.z, dw = a.w - c.w;
                d2 += dx * dx + dy * dy + dz * dz + dw * dw;
            }
            acc += __expf(-d2 * SIGMA2_INV);
        }
    }

    // Deterministic block reduction: wave64 shuffle tree + fixed-order LDS sum
    const int wlane = tid & 63, wid = tid >> 6;
    #pragma unroll
    for (int off = 32; off > 0; off >>= 1)
        acc += __shfl_down(acc, off);
    if (wlane == 0) red[wid] = acc;
    __syncthreads();
    if (tid == 0) {
        float tot = 0.f;
        #pragma unroll
        for (int w = 0; w < 16; ++w) tot += red[w];
        out[0] = tot;
    }
}

extern "C" void kernel_launch(void* const* d_in, const int* in_sizes, int n_in,
                              void* d_out, int out_size, void* d_ws, size_t ws_size,
                              hipStream_t stream) {
    const float* x    = (const float*)d_in[0];
    const int*   tags = (const int*)d_in[1];
    const int*   numH = (const int*)d_in[2];
    float*       out  = (float*)d_out;
    float*       e    = (float*)d_ws;   // e[B][NMAX][K][D] = 278,528 bytes

    scan_gather_kernel<<<SCAN_BLOCKS, SCAN_THREADS, 0, stream>>>(tags, x, e);
    loss_kernel<<<1, 1024, 0, stream>>>((const float4*)e, numH, out);
}